// Round 1
// baseline (174.472 us; speedup 1.0000x reference)
//
#include <hip/hip_runtime.h>

// FeaturesLinear: out[b,:] = sum_{h<50} user_W[fid[b,h]] * rating_W[ridx[b,h]]
//                            + item_W[item_ids[b]] + bias
// B=16384, HIST=50, D=128. Segments are contiguous (repeat(arange(B), 50)).
//
// R1: latency-bound at 62us (3.3 TB/s, VGPR=32, ~2 loads in flight).
// R2: unroll h-loop x5 -> 5 independent user_W gathers in flight per wave.
//     Keep VGPR <= 64 to hold 8 waves/SIMD.
// R3 (this session, round 0): identical re-run — previous bench attempt hit
//     an MI355X container infra failure; need baseline counters before edits.

#define BATCH     16384
#define HIST      50
#define UNROLL    5
#define DIM4      32          // 128 floats = 32 float4
#define ROWS      8           // batch rows per block
#define BLOCK     256         // ROWS * 32 lanes

__global__ __launch_bounds__(BLOCK) void features_linear_kernel(
    const int*    __restrict__ feature_ids,   // [TOTAL]
    const float*  __restrict__ ratings,       // [TOTAL]
    const int*    __restrict__ item_ids,      // [BATCH]
    const float4* __restrict__ user_W,        // [100001, 32] as float4
    const float4* __restrict__ rating_W,      // [10, 32] as float4
    const float4* __restrict__ item_W,        // [100000, 32] as float4
    const float4* __restrict__ bias,          // [32] as float4
    float4*       __restrict__ out)           // [BATCH, 32] as float4
{
    __shared__ float4 sh_rW[10 * DIM4];       // 5 KB: full rating_W table
    __shared__ int    sh_fid[ROWS * HIST];    // this block's feature ids
    __shared__ int    sh_ridx[ROWS * HIST];   // this block's rating indices

    const int tid = threadIdx.x;

    // Stage rating_W (320 float4, coalesced)
    for (int i = tid; i < 10 * DIM4; i += BLOCK) sh_rW[i] = rating_W[i];

    // Stage this block's 400 ids + rating indices
    const int base = blockIdx.x * (ROWS * HIST);
    for (int i = tid; i < ROWS * HIST; i += BLOCK) {
        sh_fid[i] = feature_ids[base + i];
        float r = ratings[base + i];
        // ratings are exact multiples of 0.5 in [0.5,5.0]; r*2 is an exact
        // integer in [1,10] -> index r*2-1 in [0,9]. Exact, no fp edge.
        sh_ridx[i] = (int)(r * 2.0f) - 1;
    }
    __syncthreads();

    const int row = tid >> 5;        // 0..7 within block
    const int d4  = tid & 31;        // float4 index within the 128-dim row
    const int b   = blockIdx.x * ROWS + row;

    // Prefetch the epilogue loads early so they overlap the gather loop.
    const int    iid = item_ids[b];
    const float4 iw  = item_W[iid * DIM4 + d4];
    const float4 bs  = bias[d4];

    float4 acc; acc.x = 0.f; acc.y = 0.f; acc.z = 0.f; acc.w = 0.f;
    const int off = row * HIST;

    for (int h = 0; h < HIST; h += UNROLL) {
        // Gather 5 indices (wave-broadcast LDS reads, free)
        const int f0 = sh_fid[off + h + 0], r0 = sh_ridx[off + h + 0];
        const int f1 = sh_fid[off + h + 1], r1 = sh_ridx[off + h + 1];
        const int f2 = sh_fid[off + h + 2], r2 = sh_ridx[off + h + 2];
        const int f3 = sh_fid[off + h + 3], r3 = sh_ridx[off + h + 3];
        const int f4 = sh_fid[off + h + 4], r4 = sh_ridx[off + h + 4];

        // 5 independent 512B coalesced gathers in flight
        const float4 u0 = user_W[f0 * DIM4 + d4];
        const float4 u1 = user_W[f1 * DIM4 + d4];
        const float4 u2 = user_W[f2 * DIM4 + d4];
        const float4 u3 = user_W[f3 * DIM4 + d4];
        const float4 u4 = user_W[f4 * DIM4 + d4];

        const float4 w0 = sh_rW[r0 * DIM4 + d4];
        const float4 w1 = sh_rW[r1 * DIM4 + d4];
        const float4 w2 = sh_rW[r2 * DIM4 + d4];
        const float4 w3 = sh_rW[r3 * DIM4 + d4];
        const float4 w4 = sh_rW[r4 * DIM4 + d4];

        acc.x += u0.x * w0.x; acc.y += u0.y * w0.y; acc.z += u0.z * w0.z; acc.w += u0.w * w0.w;
        acc.x += u1.x * w1.x; acc.y += u1.y * w1.y; acc.z += u1.z * w1.z; acc.w += u1.w * w1.w;
        acc.x += u2.x * w2.x; acc.y += u2.y * w2.y; acc.z += u2.z * w2.z; acc.w += u2.w * w2.w;
        acc.x += u3.x * w3.x; acc.y += u3.y * w3.y; acc.z += u3.z * w3.z; acc.w += u3.w * w3.w;
        acc.x += u4.x * w4.x; acc.y += u4.y * w4.y; acc.z += u4.z * w4.z; acc.w += u4.w * w4.w;
    }

    float4 o;
    o.x = acc.x + iw.x + bs.x;
    o.y = acc.y + iw.y + bs.y;
    o.z = acc.z + iw.z + bs.z;
    o.w = acc.w + iw.w + bs.w;
    out[b * DIM4 + d4] = o;
}

extern "C" void kernel_launch(void* const* d_in, const int* in_sizes, int n_in,
                              void* d_out, int out_size, void* d_ws, size_t ws_size,
                              hipStream_t stream) {
    const int*    feature_ids = (const int*)   d_in[0];
    const float*  ratings     = (const float*) d_in[1];
    // d_in[2] = segment_ids: unused (segments are contiguous by construction)
    const int*    item_ids    = (const int*)   d_in[3];
    const float4* user_W      = (const float4*)d_in[4];
    const float4* rating_W    = (const float4*)d_in[5];
    const float4* item_W      = (const float4*)d_in[6];
    const float4* bias        = (const float4*)d_in[7];
    float4*       out         = (float4*)      d_out;

    dim3 grid(BATCH / ROWS);   // 2048 blocks
    dim3 block(BLOCK);
    features_linear_kernel<<<grid, block, 0, stream>>>(
        feature_ids, ratings, item_ids, user_W, rating_W, item_W, bias, out);
}

// Round 2
// 173.587 us; speedup vs baseline: 1.0051x; 1.0051x over previous
//
#include <hip/hip_runtime.h>

// FeaturesLinear: out[b,:] = sum_{h<50} user_W[fid[b,h]] * rating_W[ridx[b,h]]
//                            + item_W[item_ids[b]] + bias
// B=16384, HIST=50, D=128. Segments are contiguous (repeat(arange(B), 50)).
//
// R1: latency-bound at 62us (3.3 TB/s, VGPR=32, ~2 loads in flight).
// R2: unroll x5 "in flight" — but VGPR=36 proves the compiler serialized it
//     (5 u + 5 w float4s alone need 40 regs). ~2 loads in flight, 63us.
// R4 (this round): force real MLP. 10-wide groups: compute all 10 addresses,
//     issue all 10 user_W loads into a live u[10] array (40 VGPR, statically
//     indexed), consume afterwards with inline LDS rating reads. item_W/bias
//     moved to epilogue to shrink loop-carried live range. Target VGPR<=64
//     so 8 waves/SIMD hold; predict 63us -> ~42us.

#define BATCH     16384
#define HIST      50
#define UNROLL    10
#define DIM4      32          // 128 floats = 32 float4
#define ROWS      8           // batch rows per block
#define BLOCK     256         // ROWS * 32 lanes

__global__ __launch_bounds__(BLOCK) void features_linear_kernel(
    const int*    __restrict__ feature_ids,   // [TOTAL]
    const float*  __restrict__ ratings,       // [TOTAL]
    const int*    __restrict__ item_ids,      // [BATCH]
    const float4* __restrict__ user_W,        // [100001, 32] as float4
    const float4* __restrict__ rating_W,      // [10, 32] as float4
    const float4* __restrict__ item_W,        // [100000, 32] as float4
    const float4* __restrict__ bias,          // [32] as float4
    float4*       __restrict__ out)           // [BATCH, 32] as float4
{
    __shared__ float4 sh_rW[10 * DIM4];       // 5 KB: full rating_W table
    __shared__ int    sh_fid[ROWS * HIST];    // this block's feature ids
    __shared__ int    sh_ridx[ROWS * HIST];   // this block's rating indices

    const int tid = threadIdx.x;

    // Stage rating_W (320 float4, coalesced)
    for (int i = tid; i < 10 * DIM4; i += BLOCK) sh_rW[i] = rating_W[i];

    // Stage this block's 400 ids + rating indices
    const int base = blockIdx.x * (ROWS * HIST);
    for (int i = tid; i < ROWS * HIST; i += BLOCK) {
        sh_fid[i] = feature_ids[base + i];
        float r = ratings[base + i];
        // ratings are exact multiples of 0.5 in [0.5,5.0]; r*2 is an exact
        // integer in [1,10] -> index r*2-1 in [0,9]. Exact, no fp edge.
        sh_ridx[i] = (int)(r * 2.0f) - 1;
    }
    __syncthreads();

    const int row = tid >> 5;        // 0..7 within block
    const int d4  = tid & 31;        // float4 index within the 128-dim row
    const int b   = blockIdx.x * ROWS + row;

    float4 acc; acc.x = 0.f; acc.y = 0.f; acc.z = 0.f; acc.w = 0.f;
    const int off = row * HIST;

    for (int h = 0; h < HIST; h += UNROLL) {
        // Read all 10 index pairs (wave-broadcast LDS reads)
        int f[UNROLL], r[UNROLL];
#pragma unroll
        for (int i = 0; i < UNROLL; ++i) {
            f[i] = sh_fid[off + h + i];
            r[i] = sh_ridx[off + h + i];
        }

        // Issue all 10 gathers before any consume: 10x 512B-per-row loads
        // genuinely in flight (u[] fully live => compiler cannot serialize).
        float4 u[UNROLL];
#pragma unroll
        for (int i = 0; i < UNROLL; ++i) {
            u[i] = user_W[f[i] * DIM4 + d4];
        }

        // Consume: inline conflict-free LDS broadcast of rating rows.
#pragma unroll
        for (int i = 0; i < UNROLL; ++i) {
            const float4 w = sh_rW[r[i] * DIM4 + d4];
            acc.x += u[i].x * w.x;
            acc.y += u[i].y * w.y;
            acc.z += u[i].z * w.z;
            acc.w += u[i].w * w.w;
        }
    }

    // Epilogue loads kept out of the loop to minimize loop-carried VGPRs.
    const int    iid = item_ids[b];
    const float4 iw  = item_W[iid * DIM4 + d4];
    const float4 bs  = bias[d4];

    float4 o;
    o.x = acc.x + iw.x + bs.x;
    o.y = acc.y + iw.y + bs.y;
    o.z = acc.z + iw.z + bs.z;
    o.w = acc.w + iw.w + bs.w;
    out[b * DIM4 + d4] = o;
}

extern "C" void kernel_launch(void* const* d_in, const int* in_sizes, int n_in,
                              void* d_out, int out_size, void* d_ws, size_t ws_size,
                              hipStream_t stream) {
    const int*    feature_ids = (const int*)   d_in[0];
    const float*  ratings     = (const float*) d_in[1];
    // d_in[2] = segment_ids: unused (segments are contiguous by construction)
    const int*    item_ids    = (const int*)   d_in[3];
    const float4* user_W      = (const float4*)d_in[4];
    const float4* rating_W    = (const float4*)d_in[5];
    const float4* item_W      = (const float4*)d_in[6];
    const float4* bias        = (const float4*)d_in[7];
    float4*       out         = (float4*)      d_out;

    dim3 grid(BATCH / ROWS);   // 2048 blocks
    dim3 block(BLOCK);
    features_linear_kernel<<<grid, block, 0, stream>>>(
        feature_ids, ratings, item_ids, user_W, rating_W, item_W, bias, out);
}

// Round 3
// 164.114 us; speedup vs baseline: 1.0631x; 1.0577x over previous
//
#include <hip/hip_runtime.h>

// FeaturesLinear: out[b,:] = sum_{h<50} user_W[fid[b,h]] * rating_W[ridx[b,h]]
//                            + item_W[item_ids[b]] + bias
// B=16384, HIST=50, D=128. Segments contiguous (repeat(arange(B), 50)).
//
// R1: VGPR=32, 62us. R2: unroll x5, 63us. R4: forced u[10], VGPR only 40, 63us.
//   Time invariant across ILP structures at 3.2-3.4 TB/s past-L2 =>
//   NOT latency-bound: bound by past-L2 random-line fill rate (~2.5 lines/cy/XCD).
//   FETCH=197MB vs 419MB gather demand (L2 hit 53%, row multiplicity 8.2/8 XCDs).
// R5 (this round): cut fill bytes, not latency. Pre-kernel converts user_W to
//   fp16 in workspace (51.2->25.6MB, streaming ~13us). Gather demand halves
//   419->210MB => fills ~197->~120MB => main kernel ~38-42us. |w|<=0.088 so
//   fp16 adds <=2e-4 absmax. Fallback to fp32 path if workspace too small.

#define BATCH     16384
#define HIST      50
#define UNROLL    10
#define DIM4      32          // 128 floats = 32 float4 (or 32 half4)
#define ROWS      8           // batch rows per block
#define BLOCK     256         // ROWS * 32 lanes
#define NROWS_U   100001
#define N4_TBL    (NROWS_U * DIM4)   // 3,200,032 float4 <-> half4 units

struct __attribute__((aligned(8))) half4 { _Float16 x, y, z, w; };  // 8 B

// ---- Pre-pass: user_W fp32 -> fp16 (streaming, ~77MB total traffic) ----
__global__ __launch_bounds__(256) void convert_kernel(
    const float4* __restrict__ src, half4* __restrict__ dst, int n4)
{
    int i = blockIdx.x * blockDim.x + threadIdx.x;
    const int stride = gridDim.x * blockDim.x;
    for (; i < n4; i += stride) {
        const float4 v = src[i];
        half4 h;
        h.x = (_Float16)v.x; h.y = (_Float16)v.y;
        h.z = (_Float16)v.z; h.w = (_Float16)v.w;
        dst[i] = h;
    }
}

// ---- Main kernel, fp16 table ----
__global__ __launch_bounds__(BLOCK) void features_linear_h16(
    const int*    __restrict__ feature_ids,   // [TOTAL]
    const float*  __restrict__ ratings,       // [TOTAL]
    const int*    __restrict__ item_ids,      // [BATCH]
    const half4*  __restrict__ user_h,        // [100001, 32] as half4 (ws)
    const float4* __restrict__ rating_W,      // [10, 32] as float4
    const float4* __restrict__ item_W,        // [100000, 32] as float4
    const float4* __restrict__ bias,          // [32] as float4
    float4*       __restrict__ out)           // [BATCH, 32] as float4
{
    __shared__ float4 sh_rW[10 * DIM4];       // 5 KB: full rating_W table
    __shared__ int    sh_fid[ROWS * HIST];
    __shared__ int    sh_ridx[ROWS * HIST];

    const int tid = threadIdx.x;

    for (int i = tid; i < 10 * DIM4; i += BLOCK) sh_rW[i] = rating_W[i];

    const int base = blockIdx.x * (ROWS * HIST);
    for (int i = tid; i < ROWS * HIST; i += BLOCK) {
        sh_fid[i] = feature_ids[base + i];
        float r = ratings[base + i];
        // ratings are exact multiples of 0.5 in [0.5,5.0]: r*2-1 in [0,9], exact.
        sh_ridx[i] = (int)(r * 2.0f) - 1;
    }
    __syncthreads();

    const int row = tid >> 5;
    const int d4  = tid & 31;
    const int b   = blockIdx.x * ROWS + row;

    float4 acc; acc.x = 0.f; acc.y = 0.f; acc.z = 0.f; acc.w = 0.f;
    const int off = row * HIST;

    for (int h = 0; h < HIST; h += UNROLL) {
        int f[UNROLL], r[UNROLL];
#pragma unroll
        for (int i = 0; i < UNROLL; ++i) {
            f[i] = sh_fid[off + h + i];
            r[i] = sh_ridx[off + h + i];
        }

        // 10 independent 8B gathers issued before any consume.
        half4 u[UNROLL];
#pragma unroll
        for (int i = 0; i < UNROLL; ++i) {
            u[i] = user_h[f[i] * DIM4 + d4];
        }

#pragma unroll
        for (int i = 0; i < UNROLL; ++i) {
            const float4 w = sh_rW[r[i] * DIM4 + d4];
            acc.x += (float)u[i].x * w.x;
            acc.y += (float)u[i].y * w.y;
            acc.z += (float)u[i].z * w.z;
            acc.w += (float)u[i].w * w.w;
        }
    }

    const int    iid = item_ids[b];
    const float4 iw  = item_W[iid * DIM4 + d4];
    const float4 bs  = bias[d4];

    float4 o;
    o.x = acc.x + iw.x + bs.x;
    o.y = acc.y + iw.y + bs.y;
    o.z = acc.z + iw.z + bs.z;
    o.w = acc.w + iw.w + bs.w;
    out[b * DIM4 + d4] = o;
}

// ---- fp32 fallback (identical to R4) if workspace too small ----
__global__ __launch_bounds__(BLOCK) void features_linear_f32(
    const int*    __restrict__ feature_ids,
    const float*  __restrict__ ratings,
    const int*    __restrict__ item_ids,
    const float4* __restrict__ user_W,
    const float4* __restrict__ rating_W,
    const float4* __restrict__ item_W,
    const float4* __restrict__ bias,
    float4*       __restrict__ out)
{
    __shared__ float4 sh_rW[10 * DIM4];
    __shared__ int    sh_fid[ROWS * HIST];
    __shared__ int    sh_ridx[ROWS * HIST];

    const int tid = threadIdx.x;
    for (int i = tid; i < 10 * DIM4; i += BLOCK) sh_rW[i] = rating_W[i];
    const int base = blockIdx.x * (ROWS * HIST);
    for (int i = tid; i < ROWS * HIST; i += BLOCK) {
        sh_fid[i] = feature_ids[base + i];
        float r = ratings[base + i];
        sh_ridx[i] = (int)(r * 2.0f) - 1;
    }
    __syncthreads();

    const int row = tid >> 5;
    const int d4  = tid & 31;
    const int b   = blockIdx.x * ROWS + row;

    float4 acc; acc.x = 0.f; acc.y = 0.f; acc.z = 0.f; acc.w = 0.f;
    const int off = row * HIST;

    for (int h = 0; h < HIST; h += UNROLL) {
        int f[UNROLL], r[UNROLL];
#pragma unroll
        for (int i = 0; i < UNROLL; ++i) {
            f[i] = sh_fid[off + h + i];
            r[i] = sh_ridx[off + h + i];
        }
        float4 u[UNROLL];
#pragma unroll
        for (int i = 0; i < UNROLL; ++i) u[i] = user_W[f[i] * DIM4 + d4];
#pragma unroll
        for (int i = 0; i < UNROLL; ++i) {
            const float4 w = sh_rW[r[i] * DIM4 + d4];
            acc.x += u[i].x * w.x;
            acc.y += u[i].y * w.y;
            acc.z += u[i].z * w.z;
            acc.w += u[i].w * w.w;
        }
    }

    const int    iid = item_ids[b];
    const float4 iw  = item_W[iid * DIM4 + d4];
    const float4 bs  = bias[d4];

    float4 o;
    o.x = acc.x + iw.x + bs.x;
    o.y = acc.y + iw.y + bs.y;
    o.z = acc.z + iw.z + bs.z;
    o.w = acc.w + iw.w + bs.w;
    out[b * DIM4 + d4] = o;
}

extern "C" void kernel_launch(void* const* d_in, const int* in_sizes, int n_in,
                              void* d_out, int out_size, void* d_ws, size_t ws_size,
                              hipStream_t stream) {
    const int*    feature_ids = (const int*)   d_in[0];
    const float*  ratings     = (const float*) d_in[1];
    // d_in[2] = segment_ids: unused (segments contiguous by construction)
    const int*    item_ids    = (const int*)   d_in[3];
    const float4* user_W      = (const float4*)d_in[4];
    const float4* rating_W    = (const float4*)d_in[5];
    const float4* item_W      = (const float4*)d_in[6];
    const float4* bias        = (const float4*)d_in[7];
    float4*       out         = (float4*)      d_out;

    dim3 grid(BATCH / ROWS);   // 2048 blocks
    dim3 block(BLOCK);

    const size_t need = (size_t)N4_TBL * sizeof(half4);   // 25.6 MB
    if (d_ws != nullptr && ws_size >= need) {
        half4* user_h = (half4*)d_ws;
        convert_kernel<<<dim3(4096), dim3(256), 0, stream>>>(
            user_W, user_h, N4_TBL);
        features_linear_h16<<<grid, block, 0, stream>>>(
            feature_ids, ratings, item_ids, user_h, rating_W, item_W, bias, out);
    } else {
        features_linear_f32<<<grid, block, 0, stream>>>(
            feature_ids, ratings, item_ids, user_W, rating_W, item_W, bias, out);
    }
}